// Round 5
// baseline (167.253 us; speedup 1.0000x reference)
//
#include <hip/hip_runtime.h>

typedef __bf16 bf16x8 __attribute__((ext_vector_type(8)));
typedef __bf16 bf16x4 __attribute__((ext_vector_type(4)));
typedef __bf16 bf16x2 __attribute__((ext_vector_type(2)));
typedef float  f32x4  __attribute__((ext_vector_type(4)));
typedef float  f32x16 __attribute__((ext_vector_type(16)));
typedef int    i32x4  __attribute__((ext_vector_type(4)));

#define MFMA16 __builtin_amdgcn_mfma_f32_16x16x32_bf16
#define MFMA32 __builtin_amdgcn_mfma_f32_32x32x16_bf16

static constexpr int BATCH = 4;
static constexpr int SEQ   = 4096;
static constexpr int CDIM  = 128;
static constexpr int HDIM  = 64;
static constexpr float FIXMAX = 16.0f;   // log2-domain safe upper bound for scores

union FB2  { bf16x2 h; int i; };
union I4B8 { i32x4 i; bf16x8 b; };

// Load 8 contiguous fp32 and convert to bf16x8
__device__ inline bf16x8 load8f_cvt(const float* __restrict__ p) {
    f32x4 a = *reinterpret_cast<const f32x4*>(p);
    f32x4 b = *reinterpret_cast<const f32x4*>(p + 4);
    bf16x8 r;
    r[0] = (__bf16)a[0]; r[1] = (__bf16)a[1]; r[2] = (__bf16)a[2]; r[3] = (__bf16)a[3];
    r[4] = (__bf16)b[0]; r[5] = (__bf16)b[1]; r[6] = (__bf16)b[2]; r[7] = (__bf16)b[3];
    return r;
}

// ---------------------------------------------------------------------------
// Fused projections, 1024 balanced blocks (16 MFMA each):
//   job 0: Q = x@Wq * qscale -> Qw[16384][64]
//   job 1: K = y@Wk          -> Kw[16384][64]
//   job 2: Vt cols   0..63   -> Vtw[4][128][4096]  (LDS-transposed store)
//   job 3: Vt cols  64..127
// ---------------------------------------------------------------------------
__global__ __launch_bounds__(256) void proj_all_kernel(
    const float* __restrict__ x, const float* __restrict__ y,
    const float* __restrict__ Wq, const float* __restrict__ Wk,
    const float* __restrict__ Wv,
    __bf16* __restrict__ Qw, __bf16* __restrict__ Kw, __bf16* __restrict__ Vtw,
    float qscale)
{
    __shared__ __bf16 Wt[64][136];    // transposed weight slice: Wt[cout][cin]
    __shared__ __bf16 Vtile[64][72];  // V transpose tile [c_local][key_local]

    const int job = blockIdx.x >> 8;
    const int bx  = blockIdx.x & 255;
    const int t    = threadIdx.x;
    const int lane = t & 63;
    const int w    = t >> 6;
    const int m    = lane & 15;
    const int quad = lane >> 4;

    if (job <= 1) {
        const float* X   = job ? y  : x;
        const float* W   = job ? Wk : Wq;
        __bf16*      out = job ? Kw : Qw;
        const float scale = job ? 1.0f : qscale;

        #pragma unroll
        for (int pass = 0; pass < 4; ++pass) {
            int flat = pass * 2048 + t * 8;
            int cin  = flat >> 6;
            int h0   = flat & 63;
            bf16x8 v = load8f_cvt(W + flat);
            #pragma unroll
            for (int j = 0; j < 8; ++j) Wt[h0 + j][cin] = v[j];
        }
        __syncthreads();

        const long row0 = (long)bx * 64 + w * 16;
        bf16x8 af[4];
        #pragma unroll
        for (int kc = 0; kc < 4; ++kc)
            af[kc] = load8f_cvt(X + (row0 + m) * 128 + kc * 32 + quad * 8);

        #pragma unroll
        for (int tn = 0; tn < 4; ++tn) {
            f32x4 acc = {0.f, 0.f, 0.f, 0.f};
            #pragma unroll
            for (int kc = 0; kc < 4; ++kc) {
                bf16x8 bfrag = *reinterpret_cast<const bf16x8*>(&Wt[tn * 16 + m][kc * 32 + quad * 8]);
                acc = MFMA16(af[kc], bfrag, acc, 0, 0, 0);
            }
            #pragma unroll
            for (int r = 0; r < 4; ++r)
                out[(row0 + quad * 4 + r) * 64 + tn * 16 + m] = (__bf16)(acc[r] * scale);
        }
    } else {
        const int cob = (job - 2) * 64;   // cout base

        // stage Wv[:, cob..cob+63] transposed
        #pragma unroll
        for (int pass = 0; pass < 4; ++pass) {
            int flat = pass * 2048 + t * 8;
            int cin  = flat >> 6;
            int co0  = flat & 63;
            bf16x8 v = load8f_cvt(Wv + cin * 128 + cob + co0);
            #pragma unroll
            for (int j = 0; j < 8; ++j) Wt[co0 + j][cin] = v[j];
        }
        __syncthreads();

        const long row0 = (long)bx * 64 + w * 16;   // key rows
        bf16x8 af[4];
        #pragma unroll
        for (int kc = 0; kc < 4; ++kc)
            af[kc] = load8f_cvt(y + (row0 + m) * 128 + kc * 32 + quad * 8);

        #pragma unroll
        for (int tn = 0; tn < 4; ++tn) {
            f32x4 acc = {0.f, 0.f, 0.f, 0.f};
            #pragma unroll
            for (int kc = 0; kc < 4; ++kc) {
                bf16x8 bfrag = *reinterpret_cast<const bf16x8*>(&Wt[tn * 16 + m][kc * 32 + quad * 8]);
                acc = MFMA16(af[kc], bfrag, acc, 0, 0, 0);
            }
            bf16x4 pk;
            #pragma unroll
            for (int r = 0; r < 4; ++r) pk[r] = (__bf16)acc[r];
            *reinterpret_cast<bf16x4*>(&Vtile[tn * 16 + m][w * 16 + quad * 4]) = pk;
        }
        __syncthreads();

        // coalesced store of the 64x64 transposed tile
        const long n    = row0 >> 12;
        const long key0 = (long)(bx * 64) & 4095;
        #pragma unroll
        for (int pass = 0; pass < 2; ++pass) {
            int idx = pass * 256 + t;
            int c   = idx >> 3;
            int ko  = (idx & 7) * 8;
            bf16x8 v = *reinterpret_cast<const bf16x8*>(&Vtile[c][ko]);
            *reinterpret_cast<bf16x8*>(Vtw + (n * 128 + cob + c) * (long)SEQ + key0 + ko) = v;
        }
    }
}

// ---------------------------------------------------------------------------
// Flash attention, LDS-free main loop.
// Block = 512 thr = 8 waves = 2 q-halves x 4 key-groups. Wave: 32 q-rows,
// 1024 keys, 32 keys/iter via 32x32x16 MFMA. Fixed-max softmax (no rescale).
// P C-layout -> B-layout via shfl_xor(32) + cndmask (no LDS). LDS only for
// the 4-way merge epilogue. Output fp32.
// ---------------------------------------------------------------------------
__global__ __launch_bounds__(512, 2) void attn_kernel(
    const __bf16* __restrict__ Q, const __bf16* __restrict__ K,
    const __bf16* __restrict__ Vt, float* __restrict__ out)
{
    __shared__ float mg[2][64][68];   // merge buffers per q-half: 64 o + l

    const int t    = threadIdx.x;
    const int lane = t & 63;
    const int w    = t >> 6;       // 0..7
    const int qh   = w & 1;        // q-half
    const int g    = w >> 1;       // key-group 0..3
    const int qc   = lane & 31;    // q column (C col), also key row / c row for A
    const int h    = lane >> 5;

    // XCD-friendly order: 2 consecutive blocks per batch -> batch n on XCDs {2n,2n+1}
    const int bx = blockIdx.x;
    const int n  = (bx >> 1) & 3;
    const int qt = (bx >> 3) * 2 + (bx & 1);    // 0..63
    const int q0 = qt * 64 + qh * 32;

    const __bf16* Qp = Q  + ((long)n * SEQ + q0) * HDIM;
    const __bf16* Kp = K  + ((long)n * SEQ + g * 1024) * HDIM;
    const __bf16* Vp = Vt + (long)n * CDIM * SEQ + g * 1024;

    // Q B-frags: B[k][q], lane(q,h) holds cols kc*16 + h*8 + j
    bf16x8 qf[4];
    #pragma unroll
    for (int kc = 0; kc < 4; ++kc)
        qf[kc] = *reinterpret_cast<const bf16x8*>(Qp + qc * HDIM + kc * 16 + h * 8);

    f32x16 o_acc[4];
    #pragma unroll
    for (int ct = 0; ct < 4; ++ct)
        #pragma unroll
        for (int i = 0; i < 16; ++i) o_acc[ct][i] = 0.f;
    float l_a = 0.f, l_b = 0.f;

    // K A-frags for iter 0: A[key][d], lane(key,h) holds d = kc*16 + h*8 + j
    bf16x8 kf[4];
    #pragma unroll
    for (int kc = 0; kc < 4; ++kc)
        kf[kc] = *reinterpret_cast<const bf16x8*>(Kp + qc * HDIM + kc * 16 + h * 8);

    for (int kt = 0; kt < 32; ++kt) {
        const int k0 = kt * 32;

        // V A-frags for this iter: Vt[ct*32+c][k0 + kc2*16 + h*8 + j]
        bf16x8 vf[8];
        #pragma unroll
        for (int ct = 0; ct < 4; ++ct)
            #pragma unroll
            for (int kc2 = 0; kc2 < 2; ++kc2)
                vf[ct * 2 + kc2] = *reinterpret_cast<const bf16x8*>(
                    Vp + (long)(ct * 32 + qc) * SEQ + k0 + kc2 * 16 + h * 8);

        // S^T = K.Q^T, pre-shifted by -FIXMAX via accumulator init
        f32x16 s;
        #pragma unroll
        for (int i = 0; i < 16; ++i) s[i] = -FIXMAX;
        #pragma unroll
        for (int kc = 0; kc < 4; ++kc)
            s = MFMA32(kf[kc], qf[kc], s, 0, 0, 0);

        // prefetch K frags for next iter (latency hidden under softmax+PV)
        if (kt < 31) {
            #pragma unroll
            for (int kc = 0; kc < 4; ++kc)
                kf[kc] = *reinterpret_cast<const bf16x8*>(
                    Kp + (long)(k0 + 32 + qc) * HDIM + kc * 16 + h * 8);
        }

        // fixed-max softmax: p = exp2(s - FIXMAX); pack bf16 pairs
        int Dw[8];
        #pragma unroll
        for (int r2 = 0; r2 < 8; ++r2) {
            float p0 = __builtin_amdgcn_exp2f(s[2 * r2]);
            float p1 = __builtin_amdgcn_exp2f(s[2 * r2 + 1]);
            l_a += p0; l_b += p1;
            FB2 u; u.h[0] = (__bf16)p0; u.h[1] = (__bf16)p1;
            Dw[r2] = u.i;
        }

        // C-layout -> B-layout: lane(q,h) needs Dw[4*kc2+2h, +1] from BOTH halves
        #pragma unroll
        for (int kc2 = 0; kc2 < 2; ++kc2) {
            int a0 = Dw[4 * kc2 + 0], a1 = Dw[4 * kc2 + 1];
            int a2 = Dw[4 * kc2 + 2], a3 = Dw[4 * kc2 + 3];
            int r0 = __shfl_xor(a0, 32, 64);
            int r1 = __shfl_xor(a1, 32, 64);
            int r2 = __shfl_xor(a2, 32, 64);
            int r3 = __shfl_xor(a3, 32, 64);
            I4B8 pb;
            pb.i[0] = h ? r2 : a0;
            pb.i[1] = h ? r3 : a1;
            pb.i[2] = h ? a2 : r0;
            pb.i[3] = h ? a3 : r1;
            #pragma unroll
            for (int ct = 0; ct < 4; ++ct)
                o_acc[ct] = MFMA32(vf[ct * 2 + kc2], pb.b, o_acc[ct], 0, 0, 0);
        }
    }

    float l_run = l_a + l_b;

    // ---- merge the 4 key-groups (pure sums thanks to fixed max) ----
    for (int gg = 1; gg < 4; ++gg) {
        if (g == gg) {
            float* dst = &mg[qh][lane][0];
            #pragma unroll
            for (int ct = 0; ct < 4; ++ct)
                #pragma unroll
                for (int i = 0; i < 16; ++i)
                    dst[ct * 16 + i] = o_acc[ct][i];
            dst[64] = l_run;
        }
        __syncthreads();
        if (g == 0) {
            const float* src = &mg[qh][lane][0];
            #pragma unroll
            for (int ct = 0; ct < 4; ++ct)
                #pragma unroll
                for (int i = 0; i < 16; ++i)
                    o_acc[ct][i] += src[ct * 16 + i];
            l_run += src[64];
        }
        __syncthreads();
    }

    if (g == 0) {
        l_run += __shfl_xor(l_run, 32, 64);   // cross-half key sum
        const float inv = 1.0f / l_run;
        const long row = (long)n * SEQ + q0 + qc;
        #pragma unroll
        for (int ct = 0; ct < 4; ++ct)
            #pragma unroll
            for (int rg = 0; rg < 4; ++rg) {
                f32x4 o;
                #pragma unroll
                for (int i = 0; i < 4; ++i) o[i] = o_acc[ct][rg * 4 + i] * inv;
                *reinterpret_cast<f32x4*>(out + row * CDIM + ct * 32 + rg * 8 + h * 4) = o;
            }
    }
}

// ---------------------------------------------------------------------------
extern "C" void kernel_launch(void* const* d_in, const int* in_sizes, int n_in,
                              void* d_out, int out_size, void* d_ws, size_t ws_size,
                              hipStream_t stream)
{
    const float* x  = (const float*)d_in[0];  // [4,4096,128] fp32
    const float* y  = (const float*)d_in[1];  // [4,4096,128] fp32
    const float* Wq = (const float*)d_in[2];  // [128,64]     fp32
    const float* Wk = (const float*)d_in[3];  // [128,64]     fp32
    const float* Wv = (const float*)d_in[4];  // [128,128]    fp32
    float* out = (float*)d_out;               // [4,4096,128] fp32

    __bf16* Qw  = (__bf16*)d_ws;                         // [4,4096,64]  2 MB
    __bf16* Kw  = Qw + (long)BATCH * SEQ * HDIM;         // [4,4096,64]  2 MB
    __bf16* Vtw = Kw + (long)BATCH * SEQ * HDIM;         // [4,128,4096] 4 MB

    // scale = H^-0.5 * log2(e), folded into Q before bf16 rounding
    const float qscale = 0.125f * 1.4426950408889634f;

    proj_all_kernel<<<dim3(1024), dim3(256), 0, stream>>>(
        x, y, Wq, Wk, Wv, Qw, Kw, Vtw, qscale);

    attn_kernel<<<dim3(256), dim3(512), 0, stream>>>(Qw, Kw, Vtw, out);
}

// Round 6
// 113.796 us; speedup vs baseline: 1.4698x; 1.4698x over previous
//
#include <hip/hip_runtime.h>

typedef __bf16 bf16x8 __attribute__((ext_vector_type(8)));
typedef __bf16 bf16x4 __attribute__((ext_vector_type(4)));
typedef __bf16 bf16x2 __attribute__((ext_vector_type(2)));
typedef float  f32x4  __attribute__((ext_vector_type(4)));
typedef float  f32x16 __attribute__((ext_vector_type(16)));
typedef int    i32x4  __attribute__((ext_vector_type(4)));

#define MFMA16 __builtin_amdgcn_mfma_f32_16x16x32_bf16
#define MFMA32 __builtin_amdgcn_mfma_f32_32x32x16_bf16

static constexpr int BATCH = 4;
static constexpr int SEQ   = 4096;
static constexpr int CDIM  = 128;
static constexpr int HDIM  = 64;
static constexpr float FIXMAX = 16.0f;   // log2-domain safe upper bound for scores

union FB2  { bf16x2 h; int i; };
union I4B8 { i32x4 i; bf16x8 b; };

// Load 8 contiguous fp32 and convert to bf16x8
__device__ inline bf16x8 load8f_cvt(const float* __restrict__ p) {
    f32x4 a = *reinterpret_cast<const f32x4*>(p);
    f32x4 b = *reinterpret_cast<const f32x4*>(p + 4);
    bf16x8 r;
    r[0] = (__bf16)a[0]; r[1] = (__bf16)a[1]; r[2] = (__bf16)a[2]; r[3] = (__bf16)a[3];
    r[4] = (__bf16)b[0]; r[5] = (__bf16)b[1]; r[6] = (__bf16)b[2]; r[7] = (__bf16)b[3];
    return r;
}

// ---------------------------------------------------------------------------
// Fragment-swizzled layouts (elements, bf16):
//   Q/K: Xswz[(KT*4 + kc)*512 + (h*32 + row)*8 + j] = X[KT*32+row][kc*16 + h*8 + j]
//        KT = global 32-row tile (0..511), kc = K-dim chunk (HDIM/16)
//   V:   Vswz[(KT*8 + ct*2 + kc2)*512 + (h*32 + c_local)*8 + j]
//          = V^T[ct*32+c_local][KT*32 + kc2*16 + h*8 + j]
// A wave's MFMA A/B fragment for a chunk is the contiguous 1KB at lane*16.
// ---------------------------------------------------------------------------

// ---------------------------------------------------------------------------
// Fused projections, 1024 blocks:
//   job 0: Qswz = swizzle(x @ Wq * qscale)
//   job 1: Kswz = swizzle(y @ Wk)
//   job 2: Vswz cols   0..63  (LDS-transposed, fragment-ordered store)
//   job 3: Vswz cols  64..127
// ---------------------------------------------------------------------------
__global__ __launch_bounds__(256) void proj_all_kernel(
    const float* __restrict__ x, const float* __restrict__ y,
    const float* __restrict__ Wq, const float* __restrict__ Wk,
    const float* __restrict__ Wv,
    __bf16* __restrict__ Qw, __bf16* __restrict__ Kw, __bf16* __restrict__ Vtw,
    float qscale)
{
    __shared__ __bf16 Wt[64][136];    // transposed weight slice: Wt[cout][cin]
    __shared__ __bf16 Vtile[64][72];  // V transpose tile [c_local][key_local]

    const int job = blockIdx.x >> 8;
    const int bx  = blockIdx.x & 255;
    const int t    = threadIdx.x;
    const int lane = t & 63;
    const int w    = t >> 6;
    const int m    = lane & 15;
    const int quad = lane >> 4;

    if (job <= 1) {
        const float* X    = job ? y  : x;
        const float* W    = job ? Wk : Wq;
        __bf16*      outp = job ? Kw : Qw;
        const float scale = job ? 1.0f : qscale;

        #pragma unroll
        for (int pass = 0; pass < 4; ++pass) {
            int flat = pass * 2048 + t * 8;
            int cin  = flat >> 6;
            int h0   = flat & 63;
            bf16x8 v = load8f_cvt(W + flat);
            #pragma unroll
            for (int j = 0; j < 8; ++j) Wt[h0 + j][cin] = v[j];
        }
        __syncthreads();

        const int row0 = bx * 64 + w * 16;
        bf16x8 af[4];
        #pragma unroll
        for (int kc = 0; kc < 4; ++kc)
            af[kc] = load8f_cvt(X + (long)(row0 + m) * 128 + kc * 32 + quad * 8);

        #pragma unroll
        for (int tn = 0; tn < 4; ++tn) {
            f32x4 acc = {0.f, 0.f, 0.f, 0.f};
            #pragma unroll
            for (int kc = 0; kc < 4; ++kc) {
                bf16x8 bfrag = *reinterpret_cast<const bf16x8*>(&Wt[tn * 16 + m][kc * 32 + quad * 8]);
                acc = MFMA16(af[kc], bfrag, acc, 0, 0, 0);
            }
            #pragma unroll
            for (int r = 0; r < 4; ++r) {
                int  kg   = row0 + quad * 4 + r;   // global row (incl. batch)
                long addr = ((long)(kg >> 5) * 4 + tn) * 512
                          + ((m >> 3) * 32 + (kg & 31)) * 8 + (m & 7);
                outp[addr] = (__bf16)(acc[r] * scale);
            }
        }
    } else {
        const int cob = (job - 2) * 64;   // cout base
        const int ct0 = (job - 2) * 2;    // 32-col group base

        // stage Wv[:, cob..cob+63] transposed
        #pragma unroll
        for (int pass = 0; pass < 4; ++pass) {
            int flat = pass * 2048 + t * 8;
            int cin  = flat >> 6;
            int co0  = flat & 63;
            bf16x8 v = load8f_cvt(Wv + cin * 128 + cob + co0);
            #pragma unroll
            for (int j = 0; j < 8; ++j) Wt[co0 + j][cin] = v[j];
        }
        __syncthreads();

        const int row0 = bx * 64 + w * 16;   // key rows
        bf16x8 af[4];
        #pragma unroll
        for (int kc = 0; kc < 4; ++kc)
            af[kc] = load8f_cvt(y + (long)(row0 + m) * 128 + kc * 32 + quad * 8);

        #pragma unroll
        for (int tn = 0; tn < 4; ++tn) {
            f32x4 acc = {0.f, 0.f, 0.f, 0.f};
            #pragma unroll
            for (int kc = 0; kc < 4; ++kc) {
                bf16x8 bfrag = *reinterpret_cast<const bf16x8*>(&Wt[tn * 16 + m][kc * 32 + quad * 8]);
                acc = MFMA16(af[kc], bfrag, acc, 0, 0, 0);
            }
            bf16x4 pk;
            #pragma unroll
            for (int r = 0; r < 4; ++r) pk[r] = (__bf16)acc[r];
            *reinterpret_cast<bf16x4*>(&Vtile[tn * 16 + m][w * 16 + quad * 4]) = pk;
        }
        __syncthreads();

        // fragment-ordered coalesced store of the 64key x 64c tile
        #pragma unroll
        for (int pp = 0; pp < 2; ++pp) {
            int i       = pp * 256 + t;
            int c_local = i & 31;
            int hh      = (i >> 5) & 1;
            int kc2     = (i >> 6) & 1;
            int ct_l    = (i >> 7) & 1;
            int kt_l    = i >> 8;
            bf16x8 v = *reinterpret_cast<const bf16x8*>(
                &Vtile[ct_l * 32 + c_local][kt_l * 32 + kc2 * 16 + hh * 8]);
            long dst = ((long)(bx * 2 + kt_l) * 8 + (ct0 + ct_l) * 2 + kc2) * 512
                     + (hh * 32 + c_local) * 8;
            *reinterpret_cast<bf16x8*>(Vtw + dst) = v;
        }
    }
}

// ---------------------------------------------------------------------------
// Flash attention, double-buffered LDS staging with fragment-linear layout.
// Block = 512 thr = 8 waves = 2 q-halves x 4 key-groups. Wave: 32 q-rows,
// 1024 keys, 32 keys/iter via 32x32x16 MFMA. Fixed-max softmax. In-register
// P transpose (shfl_xor). One barrier per iter; prefetch 2 iters ahead.
// ---------------------------------------------------------------------------
__global__ __launch_bounds__(512, 2) void attn_kernel(
    const __bf16* __restrict__ Qs, const __bf16* __restrict__ Ks,
    const __bf16* __restrict__ Vs, float* __restrict__ out)
{
    // [2 bufs x 48KB]: per buf: K[4 groups][4KB] then V[4 groups][8KB].
    // Merge epilogue overlays the first 34.8KB.
    __shared__ __align__(16) char smem[98304];

    const int t    = threadIdx.x;
    const int lane = t & 63;
    const int w    = t >> 6;       // 0..7
    const int qh   = w & 1;        // q-half
    const int g    = w >> 1;       // key-group 0..3
    const int qc   = lane & 31;
    const int h    = lane >> 5;

    const int bx = blockIdx.x;
    const int n  = (bx >> 1) & 3;
    const int qt = (bx >> 3) * 2 + (bx & 1);    // 0..63
    const int q0 = qt * 64 + qh * 32;

    // Q B-frags from swizzled layout: contiguous 1KB per chunk, lane*16
    const long QT = (long)n * 128 + (q0 >> 5);
    bf16x8 qf[4];
    #pragma unroll
    for (int kc = 0; kc < 4; ++kc)
        qf[kc] = *reinterpret_cast<const bf16x8*>(Qs + (QT * 4 + kc) * 512 + lane * 8);

    // staging descriptors: 6 chunks (1KB wave-loads) per wave
    const long KTg = (long)n * 128 + g * 32;
    const __bf16* sbase[6];
    int soff[6], sstep[6];
    if (qh == 0) {
        #pragma unroll
        for (int k = 0; k < 4; ++k) {
            sbase[k] = Ks + KTg * 2048 + k * 512 + lane * 8;
            soff[k]  = g * 4096 + k * 1024 + lane * 16;
            sstep[k] = 2048;
        }
        #pragma unroll
        for (int v2 = 0; v2 < 2; ++v2) {
            sbase[4 + v2] = Vs + KTg * 4096 + v2 * 512 + lane * 8;
            soff[4 + v2]  = 16384 + g * 8192 + v2 * 1024 + lane * 16;
            sstep[4 + v2] = 4096;
        }
    } else {
        #pragma unroll
        for (int v2 = 0; v2 < 6; ++v2) {
            sbase[v2] = Vs + KTg * 4096 + (v2 + 2) * 512 + lane * 8;
            soff[v2]  = 16384 + g * 8192 + (v2 + 2) * 1024 + lane * 16;
            sstep[v2] = 4096;
        }
    }

    f32x16 o_acc[4];
    #pragma unroll
    for (int ct = 0; ct < 4; ++ct)
        #pragma unroll
        for (int i = 0; i < 16; ++i) o_acc[ct][i] = 0.f;
    float l_a = 0.f, l_b = 0.f;

    // prologue: stage kt=0 into buf0, prefetch kt=1 into regs
    bf16x8 stg[6];
    #pragma unroll
    for (int c = 0; c < 6; ++c) stg[c] = *reinterpret_cast<const bf16x8*>(sbase[c]);
    #pragma unroll
    for (int c = 0; c < 6; ++c) *reinterpret_cast<bf16x8*>(smem + soff[c]) = stg[c];
    #pragma unroll
    for (int c = 0; c < 6; ++c)
        stg[c] = *reinterpret_cast<const bf16x8*>(sbase[c] + sstep[c]);
    __syncthreads();

    for (int kt = 0; kt < 32; ++kt) {
        const int p = kt & 1;
        const char* bufp = smem + p * 49152;
        char*       bufn = smem + (p ^ 1) * 49152;

        // write prefetched tile kt+1 into the other buffer
        if (kt < 31) {
            #pragma unroll
            for (int c = 0; c < 6; ++c)
                *reinterpret_cast<bf16x8*>(bufn + soff[c]) = stg[c];
        }
        // issue global prefetch for kt+2 (drains long before next barrier)
        if (kt < 30) {
            #pragma unroll
            for (int c = 0; c < 6; ++c)
                stg[c] = *reinterpret_cast<const bf16x8*>(sbase[c] + (kt + 2) * sstep[c]);
        }

        // K A-frags: linear ds_read_b128 sweeps
        bf16x8 kf[4];
        #pragma unroll
        for (int kc = 0; kc < 4; ++kc)
            kf[kc] = *reinterpret_cast<const bf16x8*>(bufp + g * 4096 + kc * 1024 + lane * 16);

        // S^T = K.Q^T, pre-shifted by -FIXMAX via accumulator init
        f32x16 s;
        #pragma unroll
        for (int i = 0; i < 16; ++i) s[i] = -FIXMAX;
        #pragma unroll
        for (int kc = 0; kc < 4; ++kc)
            s = MFMA32(kf[kc], qf[kc], s, 0, 0, 0);

        // fixed-max softmax: p = exp2(s - FIXMAX); pack bf16 pairs
        int Dw[8];
        #pragma unroll
        for (int r2 = 0; r2 < 8; ++r2) {
            float p0 = __builtin_amdgcn_exp2f(s[2 * r2]);
            float p1 = __builtin_amdgcn_exp2f(s[2 * r2 + 1]);
            l_a += p0; l_b += p1;
            FB2 u; u.h[0] = (__bf16)p0; u.h[1] = (__bf16)p1;
            Dw[r2] = u.i;
        }

        // C-layout -> B-layout in-register; then PV with LDS V-frags
        #pragma unroll
        for (int kc2 = 0; kc2 < 2; ++kc2) {
            int a0 = Dw[4 * kc2 + 0], a1 = Dw[4 * kc2 + 1];
            int a2 = Dw[4 * kc2 + 2], a3 = Dw[4 * kc2 + 3];
            int r0 = __shfl_xor(a0, 32, 64);
            int r1 = __shfl_xor(a1, 32, 64);
            int r2 = __shfl_xor(a2, 32, 64);
            int r3 = __shfl_xor(a3, 32, 64);
            I4B8 pb;
            pb.i[0] = h ? r2 : a0;
            pb.i[1] = h ? r3 : a1;
            pb.i[2] = h ? a2 : r0;
            pb.i[3] = h ? a3 : r1;
            #pragma unroll
            for (int ct = 0; ct < 4; ++ct) {
                bf16x8 vf = *reinterpret_cast<const bf16x8*>(
                    bufp + 16384 + g * 8192 + (ct * 2 + kc2) * 1024 + lane * 16);
                o_acc[ct] = MFMA32(vf, pb.b, o_acc[ct], 0, 0, 0);
            }
        }
        __syncthreads();
    }

    float l_run = l_a + l_b;

    // ---- merge the 4 key-groups (pure sums thanks to fixed max) ----
    float* mg = reinterpret_cast<float*>(smem);   // [2][64][68] overlay
    for (int gg = 1; gg < 4; ++gg) {
        if (g == gg) {
            float* dst = mg + (qh * 64 + lane) * 68;
            #pragma unroll
            for (int ct = 0; ct < 4; ++ct)
                #pragma unroll
                for (int i = 0; i < 16; ++i)
                    dst[ct * 16 + i] = o_acc[ct][i];
            dst[64] = l_run;
        }
        __syncthreads();
        if (g == 0) {
            const float* src = mg + (qh * 64 + lane) * 68;
            #pragma unroll
            for (int ct = 0; ct < 4; ++ct)
                #pragma unroll
                for (int i = 0; i < 16; ++i)
                    o_acc[ct][i] += src[ct * 16 + i];
            l_run += src[64];
        }
        __syncthreads();
    }

    if (g == 0) {
        l_run += __shfl_xor(l_run, 32, 64);   // cross-half key sum
        const float inv = 1.0f / l_run;
        const long row = (long)n * SEQ + q0 + qc;
        #pragma unroll
        for (int ct = 0; ct < 4; ++ct)
            #pragma unroll
            for (int rg = 0; rg < 4; ++rg) {
                f32x4 o;
                #pragma unroll
                for (int i = 0; i < 4; ++i) o[i] = o_acc[ct][rg * 4 + i] * inv;
                *reinterpret_cast<f32x4*>(out + row * CDIM + ct * 32 + rg * 8 + h * 4) = o;
            }
    }
}

// ---------------------------------------------------------------------------
extern "C" void kernel_launch(void* const* d_in, const int* in_sizes, int n_in,
                              void* d_out, int out_size, void* d_ws, size_t ws_size,
                              hipStream_t stream)
{
    const float* x  = (const float*)d_in[0];  // [4,4096,128] fp32
    const float* y  = (const float*)d_in[1];  // [4,4096,128] fp32
    const float* Wq = (const float*)d_in[2];  // [128,64]     fp32
    const float* Wk = (const float*)d_in[3];  // [128,64]     fp32
    const float* Wv = (const float*)d_in[4];  // [128,128]    fp32
    float* out = (float*)d_out;               // [4,4096,128] fp32

    __bf16* Qw  = (__bf16*)d_ws;                         // swizzled Q, 2 MB
    __bf16* Kw  = Qw + (long)BATCH * SEQ * HDIM;         // swizzled K, 2 MB
    __bf16* Vtw = Kw + (long)BATCH * SEQ * HDIM;         // swizzled V^T, 4 MB

    // scale = H^-0.5 * log2(e), folded into Q before bf16 rounding
    const float qscale = 0.125f * 1.4426950408889634f;

    proj_all_kernel<<<dim3(1024), dim3(256), 0, stream>>>(
        x, y, Wq, Wk, Wv, Qw, Kw, Vtw, qscale);

    attn_kernel<<<dim3(256), dim3(512), 0, stream>>>(Qw, Kw, Vtw, out);
}

// Round 7
// 112.619 us; speedup vs baseline: 1.4851x; 1.0105x over previous
//
#include <hip/hip_runtime.h>

typedef __bf16 bf16x8 __attribute__((ext_vector_type(8)));
typedef __bf16 bf16x4 __attribute__((ext_vector_type(4)));
typedef __bf16 bf16x2 __attribute__((ext_vector_type(2)));
typedef float  f32x4  __attribute__((ext_vector_type(4)));
typedef float  f32x16 __attribute__((ext_vector_type(16)));
typedef int    i32x4  __attribute__((ext_vector_type(4)));

#define MFMA16 __builtin_amdgcn_mfma_f32_16x16x32_bf16
#define MFMA32 __builtin_amdgcn_mfma_f32_32x32x16_bf16

static constexpr int BATCH = 4;
static constexpr int SEQ   = 4096;
static constexpr int CDIM  = 128;
static constexpr int HDIM  = 64;
static constexpr float FIXMAX = 16.0f;   // log2-domain safe upper bound for scores

union FB2  { bf16x2 h; int i; };
union I4B8 { i32x4 i; bf16x8 b; };

// Load 8 contiguous fp32 and convert to bf16x8
__device__ inline bf16x8 load8f_cvt(const float* __restrict__ p) {
    f32x4 a = *reinterpret_cast<const f32x4*>(p);
    f32x4 b = *reinterpret_cast<const f32x4*>(p + 4);
    bf16x8 r;
    r[0] = (__bf16)a[0]; r[1] = (__bf16)a[1]; r[2] = (__bf16)a[2]; r[3] = (__bf16)a[3];
    r[4] = (__bf16)b[0]; r[5] = (__bf16)b[1]; r[6] = (__bf16)b[2]; r[7] = (__bf16)b[3];
    return r;
}

// ---------------------------------------------------------------------------
// Fragment-swizzled layouts (elements, bf16):
//   Q/K: Xswz[(KT*4 + kc)*512 + (h*32 + row)*8 + j] = X[KT*32+row][kc*16 + h*8 + j]
//        KT = global 32-row tile (0..511), kc = K-dim chunk (HDIM/16)
//   V:   Vswz[(KT*8 + ct*2 + kc2)*512 + (h*32 + c_local)*8 + j]
//          = V^T[ct*32+c_local][KT*32 + kc2*16 + h*8 + j]
// A wave's MFMA A/B fragment for a chunk is the contiguous 1KB at lane*16.
// ---------------------------------------------------------------------------

// ---------------------------------------------------------------------------
// Fused projections, 1024 blocks (unchanged from round 6 — verified correct).
// ---------------------------------------------------------------------------
__global__ __launch_bounds__(256) void proj_all_kernel(
    const float* __restrict__ x, const float* __restrict__ y,
    const float* __restrict__ Wq, const float* __restrict__ Wk,
    const float* __restrict__ Wv,
    __bf16* __restrict__ Qw, __bf16* __restrict__ Kw, __bf16* __restrict__ Vtw,
    float qscale)
{
    __shared__ __bf16 Wt[64][136];    // transposed weight slice: Wt[cout][cin]
    __shared__ __bf16 Vtile[64][72];  // V transpose tile [c_local][key_local]

    const int job = blockIdx.x >> 8;
    const int bx  = blockIdx.x & 255;
    const int t    = threadIdx.x;
    const int lane = t & 63;
    const int w    = t >> 6;
    const int m    = lane & 15;
    const int quad = lane >> 4;

    if (job <= 1) {
        const float* X    = job ? y  : x;
        const float* W    = job ? Wk : Wq;
        __bf16*      outp = job ? Kw : Qw;
        const float scale = job ? 1.0f : qscale;

        #pragma unroll
        for (int pass = 0; pass < 4; ++pass) {
            int flat = pass * 2048 + t * 8;
            int cin  = flat >> 6;
            int h0   = flat & 63;
            bf16x8 v = load8f_cvt(W + flat);
            #pragma unroll
            for (int j = 0; j < 8; ++j) Wt[h0 + j][cin] = v[j];
        }
        __syncthreads();

        const int row0 = bx * 64 + w * 16;
        bf16x8 af[4];
        #pragma unroll
        for (int kc = 0; kc < 4; ++kc)
            af[kc] = load8f_cvt(X + (long)(row0 + m) * 128 + kc * 32 + quad * 8);

        #pragma unroll
        for (int tn = 0; tn < 4; ++tn) {
            f32x4 acc = {0.f, 0.f, 0.f, 0.f};
            #pragma unroll
            for (int kc = 0; kc < 4; ++kc) {
                bf16x8 bfrag = *reinterpret_cast<const bf16x8*>(&Wt[tn * 16 + m][kc * 32 + quad * 8]);
                acc = MFMA16(af[kc], bfrag, acc, 0, 0, 0);
            }
            #pragma unroll
            for (int r = 0; r < 4; ++r) {
                int  kg   = row0 + quad * 4 + r;   // global row (incl. batch)
                long addr = ((long)(kg >> 5) * 4 + tn) * 512
                          + ((m >> 3) * 32 + (kg & 31)) * 8 + (m & 7);
                outp[addr] = (__bf16)(acc[r] * scale);
            }
        }
    } else {
        const int cob = (job - 2) * 64;   // cout base
        const int ct0 = (job - 2) * 2;    // 32-col group base

        // stage Wv[:, cob..cob+63] transposed
        #pragma unroll
        for (int pass = 0; pass < 4; ++pass) {
            int flat = pass * 2048 + t * 8;
            int cin  = flat >> 6;
            int co0  = flat & 63;
            bf16x8 v = load8f_cvt(Wv + cin * 128 + cob + co0);
            #pragma unroll
            for (int j = 0; j < 8; ++j) Wt[co0 + j][cin] = v[j];
        }
        __syncthreads();

        const int row0 = bx * 64 + w * 16;   // key rows
        bf16x8 af[4];
        #pragma unroll
        for (int kc = 0; kc < 4; ++kc)
            af[kc] = load8f_cvt(y + (long)(row0 + m) * 128 + kc * 32 + quad * 8);

        #pragma unroll
        for (int tn = 0; tn < 4; ++tn) {
            f32x4 acc = {0.f, 0.f, 0.f, 0.f};
            #pragma unroll
            for (int kc = 0; kc < 4; ++kc) {
                bf16x8 bfrag = *reinterpret_cast<const bf16x8*>(&Wt[tn * 16 + m][kc * 32 + quad * 8]);
                acc = MFMA16(af[kc], bfrag, acc, 0, 0, 0);
            }
            bf16x4 pk;
            #pragma unroll
            for (int r = 0; r < 4; ++r) pk[r] = (__bf16)acc[r];
            *reinterpret_cast<bf16x4*>(&Vtile[tn * 16 + m][w * 16 + quad * 4]) = pk;
        }
        __syncthreads();

        // fragment-ordered coalesced store of the 64key x 64c tile
        #pragma unroll
        for (int pp = 0; pp < 2; ++pp) {
            int i       = pp * 256 + t;
            int c_local = i & 31;
            int hh      = (i >> 5) & 1;
            int kc2     = (i >> 6) & 1;
            int ct_l    = (i >> 7) & 1;
            int kt_l    = i >> 8;
            bf16x8 v = *reinterpret_cast<const bf16x8*>(
                &Vtile[ct_l * 32 + c_local][kt_l * 32 + kc2 * 16 + hh * 8]);
            long dst = ((long)(bx * 2 + kt_l) * 8 + (ct0 + ct_l) * 2 + kc2) * 512
                     + (hh * 32 + c_local) * 8;
            *reinterpret_cast<bf16x8*>(Vtw + dst) = v;
        }
    }
}

// ---------------------------------------------------------------------------
// One flash step for 32 keys: S^T MFMA + fixed-max softmax + in-register
// P transpose + PV MFMA. All operands in registers.
// ---------------------------------------------------------------------------
__device__ __forceinline__ void attn_step(
    const bf16x8 (&kf)[4], const bf16x8 (&vf)[8], const bf16x8 (&qf)[4],
    f32x16 (&o_acc)[4], float& l_a, float& l_b, int h)
{
    f32x16 s;
    #pragma unroll
    for (int i = 0; i < 16; ++i) s[i] = -FIXMAX;
    #pragma unroll
    for (int kc = 0; kc < 4; ++kc)
        s = MFMA32(kf[kc], qf[kc], s, 0, 0, 0);

    int Dw[8];
    #pragma unroll
    for (int r2 = 0; r2 < 8; ++r2) {
        float p0 = __builtin_amdgcn_exp2f(s[2 * r2]);
        float p1 = __builtin_amdgcn_exp2f(s[2 * r2 + 1]);
        l_a += p0; l_b += p1;
        FB2 u; u.h[0] = (__bf16)p0; u.h[1] = (__bf16)p1;
        Dw[r2] = u.i;
    }

    #pragma unroll
    for (int kc2 = 0; kc2 < 2; ++kc2) {
        int a0 = Dw[4 * kc2 + 0], a1 = Dw[4 * kc2 + 1];
        int a2 = Dw[4 * kc2 + 2], a3 = Dw[4 * kc2 + 3];
        int r0 = __shfl_xor(a0, 32, 64);
        int r1 = __shfl_xor(a1, 32, 64);
        int r2 = __shfl_xor(a2, 32, 64);
        int r3 = __shfl_xor(a3, 32, 64);
        I4B8 pb;
        pb.i[0] = h ? r2 : a0;
        pb.i[1] = h ? r3 : a1;
        pb.i[2] = h ? a2 : r0;
        pb.i[3] = h ? a3 : r1;
        #pragma unroll
        for (int ct = 0; ct < 4; ++ct)
            o_acc[ct] = MFMA32(vf[ct * 2 + kc2], pb.b, o_acc[ct], 0, 0, 0);
    }
}

// ---------------------------------------------------------------------------
// Flash attention, barrier-free main loop: fragments loaded directly from the
// swizzled global workspace (each load = one coalesced dwordx4 at lane*16),
// register double-buffer pipelined one iter ahead, unrolled by 2. LDS used
// only for the 4-way key-group merge epilogue.
// Block = 512 thr = 8 waves = 2 q-halves x 4 key-groups; 32 q-rows/wave.
// ---------------------------------------------------------------------------
__global__ __launch_bounds__(512, 2) void attn_kernel(
    const __bf16* __restrict__ Qs, const __bf16* __restrict__ Ks,
    const __bf16* __restrict__ Vs, float* __restrict__ out)
{
    __shared__ float mg[2][64][68];   // merge buffers per q-half (epilogue only)

    const int t    = threadIdx.x;
    const int lane = t & 63;
    const int w    = t >> 6;       // 0..7
    const int qh   = w & 1;        // q-half
    const int g    = w >> 1;       // key-group 0..3
    const int qc   = lane & 31;
    const int h    = lane >> 5;

    const int bx = blockIdx.x;
    const int n  = (bx >> 1) & 3;
    const int qt = (bx >> 3) * 2 + (bx & 1);    // 0..63
    const int q0 = qt * 64 + qh * 32;

    // Q B-frags: contiguous 1KB per chunk
    const long QT = (long)n * 128 + (q0 >> 5);
    bf16x8 qf[4];
    #pragma unroll
    for (int kc = 0; kc < 4; ++kc)
        qf[kc] = *reinterpret_cast<const bf16x8*>(Qs + (QT * 4 + kc) * 512 + lane * 8);

    // fragment base pointers for this wave's key stream (tile = n*128+g*32+kt)
    const __bf16* kb = Ks + ((long)n * 128 + g * 32) * 2048 + lane * 8;
    const __bf16* vb = Vs + ((long)n * 128 + g * 32) * 4096 + lane * 8;

    f32x16 o_acc[4];
    #pragma unroll
    for (int ct = 0; ct < 4; ++ct)
        #pragma unroll
        for (int i = 0; i < 16; ++i) o_acc[ct][i] = 0.f;
    float l_a = 0.f, l_b = 0.f;

    bf16x8 kfA[4], vfA[8], kfB[4], vfB[8];

    // prologue: load iter 0 into A
    #pragma unroll
    for (int kc = 0; kc < 4; ++kc)
        kfA[kc] = *reinterpret_cast<const bf16x8*>(kb + kc * 512);
    #pragma unroll
    for (int c = 0; c < 8; ++c)
        vfA[c] = *reinterpret_cast<const bf16x8*>(vb + c * 512);

    for (int kt = 0; kt < 32; kt += 2) {
        // issue loads for kt+1 into B (always valid: kt+1 <= 31)
        {
            const __bf16* kp = kb + (long)(kt + 1) * 2048;
            const __bf16* vp = vb + (long)(kt + 1) * 4096;
            #pragma unroll
            for (int kc = 0; kc < 4; ++kc)
                kfB[kc] = *reinterpret_cast<const bf16x8*>(kp + kc * 512);
            #pragma unroll
            for (int c = 0; c < 8; ++c)
                vfB[c] = *reinterpret_cast<const bf16x8*>(vp + c * 512);
        }
        attn_step(kfA, vfA, qf, o_acc, l_a, l_b, h);

        // issue loads for kt+2 into A
        if (kt < 30) {
            const __bf16* kp = kb + (long)(kt + 2) * 2048;
            const __bf16* vp = vb + (long)(kt + 2) * 4096;
            #pragma unroll
            for (int kc = 0; kc < 4; ++kc)
                kfA[kc] = *reinterpret_cast<const bf16x8*>(kp + kc * 512);
            #pragma unroll
            for (int c = 0; c < 8; ++c)
                vfA[c] = *reinterpret_cast<const bf16x8*>(vp + c * 512);
        }
        attn_step(kfB, vfB, qf, o_acc, l_a, l_b, h);
    }

    float l_run = l_a + l_b;

    // ---- merge the 4 key-groups (pure sums thanks to fixed max) ----
    for (int gg = 1; gg < 4; ++gg) {
        if (g == gg) {
            float* dst = &mg[qh][lane][0];
            #pragma unroll
            for (int ct = 0; ct < 4; ++ct)
                #pragma unroll
                for (int i = 0; i < 16; ++i)
                    dst[ct * 16 + i] = o_acc[ct][i];
            dst[64] = l_run;
        }
        __syncthreads();
        if (g == 0) {
            const float* src = &mg[qh][lane][0];
            #pragma unroll
            for (int ct = 0; ct < 4; ++ct)
                #pragma unroll
                for (int i = 0; i < 16; ++i)
                    o_acc[ct][i] += src[ct * 16 + i];
            l_run += src[64];
        }
        __syncthreads();
    }

    if (g == 0) {
        l_run += __shfl_xor(l_run, 32, 64);   // cross-half key sum
        const float inv = 1.0f / l_run;
        const long row = (long)n * SEQ + q0 + qc;
        #pragma unroll
        for (int ct = 0; ct < 4; ++ct)
            #pragma unroll
            for (int rg = 0; rg < 4; ++rg) {
                f32x4 o;
                #pragma unroll
                for (int i = 0; i < 4; ++i) o[i] = o_acc[ct][rg * 4 + i] * inv;
                *reinterpret_cast<f32x4*>(out + row * CDIM + ct * 32 + rg * 8 + h * 4) = o;
            }
    }
}

// ---------------------------------------------------------------------------
extern "C" void kernel_launch(void* const* d_in, const int* in_sizes, int n_in,
                              void* d_out, int out_size, void* d_ws, size_t ws_size,
                              hipStream_t stream)
{
    const float* x  = (const float*)d_in[0];  // [4,4096,128] fp32
    const float* y  = (const float*)d_in[1];  // [4,4096,128] fp32
    const float* Wq = (const float*)d_in[2];  // [128,64]     fp32
    const float* Wk = (const float*)d_in[3];  // [128,64]     fp32
    const float* Wv = (const float*)d_in[4];  // [128,128]    fp32
    float* out = (float*)d_out;               // [4,4096,128] fp32

    __bf16* Qw  = (__bf16*)d_ws;                         // swizzled Q, 2 MB
    __bf16* Kw  = Qw + (long)BATCH * SEQ * HDIM;         // swizzled K, 2 MB
    __bf16* Vtw = Kw + (long)BATCH * SEQ * HDIM;         // swizzled V^T, 4 MB

    // scale = H^-0.5 * log2(e), folded into Q before bf16 rounding
    const float qscale = 0.125f * 1.4426950408889634f;

    proj_all_kernel<<<dim3(1024), dim3(256), 0, stream>>>(
        x, y, Wq, Wk, Wv, Qw, Kw, Vtw, qscale);

    attn_kernel<<<dim3(256), dim3(512), 0, stream>>>(Qw, Kw, Vtw, out);
}